// Round 15
// baseline (3753.808 us; speedup 1.0000x reference)
//
#include <hip/hip_runtime.h>
#include <math.h>

#define B_   4
#define L_   2048
#define H_   12
#define DH_  64
#define DM_  768
#define DFF_ 3072
#define NL_  12
#define M_   (B_*L_)
#define NCH_ 8               // kv partial chunks (each block covers 256 seq rows)
#define QLD_ 2304            // fused QKV row stride
#define LN_EPS_  1e-5f
#define EMB_EPS_ 1e-12f
#define ATT_EPS_ 1e-6f

typedef unsigned short u16;
typedef __bf16 bf16x8 __attribute__((ext_vector_type(8)));
typedef float  f32x4  __attribute__((ext_vector_type(4)));

__device__ __forceinline__ u16 f2b(float f) {
  unsigned u = __builtin_bit_cast(unsigned, f);
  u += 0x7fffu + ((u >> 16) & 1u);
  return (u16)(u >> 16);
}
__device__ __forceinline__ float b2f(u16 s) {
  return __builtin_bit_cast(float, (unsigned)((unsigned)s << 16));
}
__device__ __forceinline__ float wredsum(float v) {
  #pragma unroll
  for (int o = 32; o > 0; o >>= 1) v += __shfl_xor(v, o, 64);
  return v;
}
// async global->LDS, 16B per lane; lds dest is wave-uniform base + lane*16
__device__ __forceinline__ void gld16(const void* g, void* l) {
  __builtin_amdgcn_global_load_lds(
      (const __attribute__((address_space(1))) void*)g,
      (__attribute__((address_space(3))) void*)l, 16, 0, 0);
}

// ---------------- weight f32 -> bf16 (layout-preserving) ----------------
__global__ __launch_bounds__(256) void cvt_bf16(const float* __restrict__ in,
                                                u16* __restrict__ out, int n4) {
  int i = blockIdx.x * 256 + threadIdx.x;
  if (i >= n4) return;
  float4 f = ((const float4*)in)[i];
  ushort4 o;
  o.x = f2b(f.x); o.y = f2b(f.y); o.z = f2b(f.z); o.w = f2b(f.w);
  ((ushort4*)out)[i] = o;
}

// ---------------- weight f32 -> bf16 into fused [NL][2304][768] at row offset ro ----------------
__global__ __launch_bounds__(256) void cvt_bf16_qkv(const float* __restrict__ in,
                                                    u16* __restrict__ out, int ro) {
  int i = blockIdx.x * 256 + threadIdx.x;   // over NL*768*768/4
  if (i >= NL_*DM_*DM_/4) return;
  int row = i / 192;            // global row (l*768 + r), 192 float4 per row
  int c4  = (i % 192) * 4;
  int l = row / DM_, r = row % DM_;
  float4 f = ((const float4*)in)[i];
  ushort4 o;
  o.x = f2b(f.x); o.y = f2b(f.y); o.z = f2b(f.z); o.w = f2b(f.w);
  *(ushort4*)(out + ((size_t)l*QLD_ + ro + r)*DM_ + c4) = o;
}

// ---------------- fused bias [NL][2304] ----------------
__global__ __launch_bounds__(256) void fuse_bias(const float* __restrict__ bq,
    const float* __restrict__ bk, const float* __restrict__ bv, float* __restrict__ out) {
  int i = blockIdx.x * 256 + threadIdx.x;
  if (i >= NL_*QLD_) return;
  int l = i / QLD_, r = i % QLD_;
  float v = r < DM_ ? bq[l*DM_ + r] : r < 2*DM_ ? bk[l*DM_ + r - DM_] : bv[l*DM_ + r - 2*DM_];
  out[i] = v;
}

// ---------------- embedding + LN ----------------
__global__ __launch_bounds__(256) void embed_ln(
    const int* __restrict__ ids, const int* __restrict__ tts,
    const float* __restrict__ we, const float* __restrict__ pe,
    const float* __restrict__ te, const float* __restrict__ lw,
    const float* __restrict__ lb, float* __restrict__ x32, u16* __restrict__ xb)
{
  int row  = blockIdx.x * 4 + (threadIdx.x >> 6);
  int lane = threadIdx.x & 63;
  int l  = row & (L_ - 1);
  int id = ids[row];
  int tt = tts[row];
  const float* wr = we + (size_t)id * DM_;
  const float* pr = pe + (size_t)l  * DM_;
  const float* tr = te + (size_t)tt * DM_;
  float v[12]; float s = 0.f;
  #pragma unroll
  for (int j = 0; j < 12; j++) { int c = j*64 + lane; v[j] = wr[c] + pr[c] + tr[c]; s += v[j]; }
  s = wredsum(s);
  float m = s * (1.f/768.f);
  float q = 0.f;
  #pragma unroll
  for (int j = 0; j < 12; j++) { float d = v[j] - m; q += d*d; }
  q = wredsum(q);
  float rs = rsqrtf(q * (1.f/768.f) + EMB_EPS_);
  float* xo = x32 + (size_t)row * DM_;
  u16*   bo = xb  + (size_t)row * DM_;
  #pragma unroll
  for (int j = 0; j < 12; j++) {
    int c = j*64 + lane;
    float o = (v[j] - m) * rs * lw[c] + lb[c];
    xo[c] = o; bo[c] = f2b(o);
  }
}

// ---------------- residual + LN (x32 f32 master; t is bf16) ----------------
__global__ __launch_bounds__(256) void ln_res(
    float* __restrict__ x32, const u16* __restrict__ t16,
    const float* __restrict__ lw, const float* __restrict__ lb,
    u16* __restrict__ xb, float eps)
{
  int row  = blockIdx.x * 4 + (threadIdx.x >> 6);
  int lane = threadIdx.x & 63;
  float* xr = x32 + (size_t)row * DM_;
  const u16* tr = t16 + (size_t)row * DM_;
  float v[12]; float s = 0.f;
  #pragma unroll
  for (int j = 0; j < 12; j++) { int c = j*64 + lane; v[j] = xr[c] + b2f(tr[c]); s += v[j]; }
  s = wredsum(s);
  float m = s * (1.f/768.f);
  float q = 0.f;
  #pragma unroll
  for (int j = 0; j < 12; j++) { float d = v[j] - m; q += d*d; }
  q = wredsum(q);
  float rs = rsqrtf(q * (1.f/768.f) + eps);
  u16* bo = xb + (size_t)row * DM_;
  #pragma unroll
  for (int j = 0; j < 12; j++) {
    int c = j*64 + lane;
    float o = (v[j] - m) * rs * lw[c] + lb[c];
    xr[c] = o; bo[c] = f2b(o);
  }
}

// ---------------- GEMM: C[M,N] = A[M,K] @ Bw[N,K]^T + bias (R6-proven structure) ----------------
// BM=BN=128, BK=64, single buffer, 2 barriers/iter. Both-sides XOR swizzle:
// linear gld16 dest, pre-swizzled global source group (lane&7)^(row&7),
// read group (kk*4+g)^(lr&7).
// EPI: 0 = bf16 out, 2 = gelu(erf)->bf16, 4 = QKV fused (elu+1 on cols<1536)
template<int EPI>
__global__ __launch_bounds__(256)
void gemm_gl(const u16* __restrict__ A, const u16* __restrict__ Bw,
             const float* __restrict__ bias,
             u16* __restrict__ Co,
             int M, int N, int K, int ldc)
{
  __shared__ alignas(16) u16 sA[128*64];
  __shared__ alignas(16) u16 sB[128*64];
  const int tid  = threadIdx.x;
  const int lane = tid & 63;
  const int w    = tid >> 6;
  const int wr = w >> 1, wc = w & 1;
  const int row0 = blockIdx.x * 128;
  const int col0 = blockIdx.y * 128;
  const int lr = lane & 15;
  const int g  = lane >> 4;            // 16B-group (0..3) within a 32-col k-slice
  const int srow = lane >> 3;          // row within 8-row staging slab
  const int acol = (((lane & 7) ^ srow) * 8);  // swizzled global source col (u16)

  f32x4 acc[4][4];
  #pragma unroll
  for (int i = 0; i < 4; i++)
    #pragma unroll
    for (int j = 0; j < 4; j++) acc[i][j] = (f32x4){0.f,0.f,0.f,0.f};

  const u16* Ap = A  + (size_t)row0 * K;
  const u16* Bp = Bw + (size_t)col0 * K;

  for (int kt = 0; kt < K; kt += 64) {
    #pragma unroll
    for (int j = 0; j < 4; j++) {   // wave w stages A rows [w*32, w*32+32) and B likewise
      gld16(Ap + (size_t)(w*32 + j*8 + srow)*K + kt + acol, sA + (w*32 + j*8)*64);
      gld16(Bp + (size_t)(w*32 + j*8 + srow)*K + kt + acol, sB + (w*32 + j*8)*64);
    }
    __syncthreads();                 // drains vmcnt before barrier
    #pragma unroll
    for (int kk = 0; kk < 2; kk++) {
      const int gg = ((kk*4 + g) ^ (lr & 7)) * 8;
      bf16x8 af[4], bv[4];
      #pragma unroll
      for (int m = 0; m < 4; m++) af[m] = *(const bf16x8*)(sA + (wr*64 + m*16 + lr)*64 + gg);
      #pragma unroll
      for (int n = 0; n < 4; n++) bv[n] = *(const bf16x8*)(sB + (wc*64 + n*16 + lr)*64 + gg);
      #pragma unroll
      for (int m = 0; m < 4; m++)
        #pragma unroll
        for (int n = 0; n < 4; n++)
          acc[m][n] = __builtin_amdgcn_mfma_f32_16x16x32_bf16(af[m], bv[n], acc[m][n], 0, 0, 0);
    }
    __syncthreads();                 // reads done before next stage overwrites
  }

  #pragma unroll
  for (int m = 0; m < 4; m++) {
    const int row_b = row0 + wr*64 + m*16 + (lane >> 4) * 4;
    #pragma unroll
    for (int n = 0; n < 4; n++) {
      const int col = col0 + wc*64 + n*16 + lr;
      const float bvb = bias[col];
      #pragma unroll
      for (int r = 0; r < 4; r++) {
        float v = acc[m][n][r] + bvb;
        if constexpr (EPI == 4) { if (col < 2*DM_) v = v > 0.f ? v + 1.f : __expf(v); }
        if constexpr (EPI == 2) v = 0.5f * v * (1.f + erff(v * 0.70710678118654752f));
        Co[(size_t)(row_b + r) * ldc + col] = f2b(v);
      }
    }
  }
}

// ---------------- tall GEMM: BM=256, BN=128, BK=64 — 2 row-halves per wave ----------------
// Same staging/XOR-swizzle; per barrier-pair each wave does 64 MFMA (2x gemm_gl).
// 85 FLOP/staged-byte (vs 64). For the K=768 FFN1 shape. EPI 2 = gelu(erf)->bf16.
__global__ __launch_bounds__(256)
void gemm_m2(const u16* __restrict__ A, const u16* __restrict__ Bw,
             const float* __restrict__ bias, u16* __restrict__ Co,
             int M, int N, int K, int ldc)
{
  __shared__ alignas(16) u16 sA[256*64];   // 32 KB
  __shared__ alignas(16) u16 sB[128*64];   // 16 KB
  const int tid  = threadIdx.x;
  const int lane = tid & 63;
  const int w    = tid >> 6;
  const int wr = w >> 1, wc = w & 1;
  const int row0 = blockIdx.x * 256;
  const int col0 = blockIdx.y * 128;
  const int lr = lane & 15;
  const int g  = lane >> 4;
  const int srow = lane >> 3;
  const int acol = (((lane & 7) ^ srow) * 8);

  f32x4 acc[2][4][4];
  #pragma unroll
  for (int h = 0; h < 2; h++)
    #pragma unroll
    for (int i = 0; i < 4; i++)
      #pragma unroll
      for (int j = 0; j < 4; j++) acc[h][i][j] = (f32x4){0.f,0.f,0.f,0.f};

  const u16* Ap = A  + (size_t)row0 * K;
  const u16* Bp = Bw + (size_t)col0 * K;

  for (int kt = 0; kt < K; kt += 64) {
    #pragma unroll
    for (int j = 0; j < 8; j++)   // A: wave w stages rows [w*64, w*64+64)
      gld16(Ap + (size_t)(w*64 + j*8 + srow)*K + kt + acol, sA + (w*64 + j*8)*64);
    #pragma unroll
    for (int j = 0; j < 4; j++)   // B: wave w stages rows [w*32, w*32+32)
      gld16(Bp + (size_t)(w*32 + j*8 + srow)*K + kt + acol, sB + (w*32 + j*8)*64);
    __syncthreads();
    #pragma unroll
    for (int kk = 0; kk < 2; kk++) {
      const int gg = ((kk*4 + g) ^ (lr & 7)) * 8;
      bf16x8 bv[4];
      #pragma unroll
      for (int n = 0; n < 4; n++) bv[n] = *(const bf16x8*)(sB + (wc*64 + n*16 + lr)*64 + gg);
      #pragma unroll
      for (int h = 0; h < 2; h++)
        #pragma unroll
        for (int m = 0; m < 4; m++) {
          bf16x8 af = *(const bf16x8*)(sA + (h*128 + wr*64 + m*16 + lr)*64 + gg);
          #pragma unroll
          for (int n = 0; n < 4; n++)
            acc[h][m][n] = __builtin_amdgcn_mfma_f32_16x16x32_bf16(af, bv[n], acc[h][m][n], 0, 0, 0);
        }
    }
    __syncthreads();
  }

  #pragma unroll
  for (int h = 0; h < 2; h++)
    #pragma unroll
    for (int m = 0; m < 4; m++) {
      const int row_b = row0 + h*128 + wr*64 + m*16 + (lane >> 4) * 4;
      #pragma unroll
      for (int n = 0; n < 4; n++) {
        const int col = col0 + wc*64 + n*16 + lr;
        const float bvb = bias[col];
        #pragma unroll
        for (int r = 0; r < 4; r++) {
          float v = acc[h][m][n][r] + bvb;
          v = 0.5f * v * (1.f + erff(v * 0.70710678118654752f));
          Co[(size_t)(row_b + r) * ldc + col] = f2b(v);
        }
      }
    }
}

// ---------------- skinny-N GEMM: BM=128, BN=64, BK=64, bf16 out + bias ----------------
__global__ __launch_bounds__(256)
void gemm_n64(const u16* __restrict__ A, const u16* __restrict__ Bw,
              const float* __restrict__ bias, u16* __restrict__ Ct,
              int M, int N, int K, int ldc)
{
  __shared__ alignas(16) u16 sA[128*64];
  __shared__ alignas(16) u16 sB[64*64];
  const int tid  = threadIdx.x;
  const int lane = tid & 63;
  const int w    = tid >> 6;
  const int row0 = blockIdx.x * 128;
  const int col0 = blockIdx.y * 64;
  const int lr = lane & 15;
  const int g  = lane >> 4;
  const int srow = lane >> 3;
  const int acol = (((lane & 7) ^ srow) * 8);

  f32x4 acc[2][4];
  #pragma unroll
  for (int i = 0; i < 2; i++)
    #pragma unroll
    for (int j = 0; j < 4; j++) acc[i][j] = (f32x4){0.f,0.f,0.f,0.f};

  const u16* ApA = A  + (size_t)(row0)*K;
  const u16* BpB = Bw + (size_t)(col0)*K;

  for (int kt = 0; kt < K; kt += 64) {
    #pragma unroll
    for (int j = 0; j < 4; j++)
      gld16(ApA + (size_t)(w*32 + j*8 + srow)*K + kt + acol, sA + (w*32 + j*8)*64);
    #pragma unroll
    for (int j = 0; j < 2; j++)
      gld16(BpB + (size_t)(w*16 + j*8 + srow)*K + kt + acol, sB + (w*16 + j*8)*64);
    __syncthreads();
    #pragma unroll
    for (int kk = 0; kk < 2; kk++) {
      const int gg = ((kk*4 + g) ^ (lr & 7)) * 8;
      bf16x8 af[2], bv[4];
      #pragma unroll
      for (int m = 0; m < 2; m++) af[m] = *(const bf16x8*)(sA + (w*32 + m*16 + lr)*64 + gg);
      #pragma unroll
      for (int n = 0; n < 4; n++) bv[n] = *(const bf16x8*)(sB + (n*16 + lr)*64 + gg);
      #pragma unroll
      for (int m = 0; m < 2; m++)
        #pragma unroll
        for (int n = 0; n < 4; n++)
          acc[m][n] = __builtin_amdgcn_mfma_f32_16x16x32_bf16(af[m], bv[n], acc[m][n], 0, 0, 0);
    }
    __syncthreads();
  }

  #pragma unroll
  for (int m = 0; m < 2; m++) {
    const int row_b = row0 + w*32 + m*16 + (lane >> 4) * 4;
    #pragma unroll
    for (int n = 0; n < 4; n++) {
      const int col = col0 + n*16 + lr;
      const float bvb = bias[col];
      #pragma unroll
      for (int r = 0; r < 4; r++)
        Ct[(size_t)(row_b + r) * ldc + col] = f2b(acc[m][n][r] + bvb);
    }
  }
}

// ---------------- KV stage 1: per-(bh, 256-seq-chunk) partial outer product ----------------
__global__ __launch_bounds__(256) void kv_part(
    const u16* __restrict__ qkv, const float* __restrict__ mask,
    float* __restrict__ kvp, float* __restrict__ ksp)
{
  __shared__ float sK[64*64];
  __shared__ float sV[64*64];
  const int bh = blockIdx.x;
  const int b = bh / H_, h = bh % H_;
  const int s0 = blockIdx.y * 256;
  const int t = threadIdx.x;
  const u16* kb = qkv + DM_;
  const u16* vb = qkv + 2*DM_;
  const int m0 = (t >> 4) * 4;
  const int d0 = (t & 15) * 4;
  float acc[4][4] = {{0.f}};
  float ks[4] = {0.f, 0.f, 0.f, 0.f};

  for (int cc = 0; cc < 4; cc++) {
    __syncthreads();   // previous sub-chunk's reads done before overwrite
    #pragma unroll
    for (int r = 0; r < 2; r++) {
      int idx = r*256 + t;
      int sr = idx >> 3;
      int c  = (idx & 7) * 8;
      int sg = s0 + cc*64 + sr;
      size_t base = ((size_t)(b*L_ + sg)) * QLD_ + h*DH_ + c;
      uint4 kk = *(const uint4*)(kb + base);
      uint4 vv = *(const uint4*)(vb + base);
      float mk = mask[b*L_ + sg];
      const u16* kp = (const u16*)&kk;
      const u16* vp = (const u16*)&vv;
      #pragma unroll
      for (int j = 0; j < 8; j++) {
        sK[sr*64 + c + j] = b2f(kp[j]) * mk;
        sV[sr*64 + c + j] = b2f(vp[j]);
      }
    }
    __syncthreads();
    for (int s = 0; s < 64; s++) {
      float4 vm = *(const float4*)(sV + s*64 + m0);
      float4 kk = *(const float4*)(sK + s*64 + d0);
      float vmv[4] = {vm.x, vm.y, vm.z, vm.w};
      float kkv[4] = {kk.x, kk.y, kk.z, kk.w};
      #pragma unroll
      for (int i = 0; i < 4; i++)
        #pragma unroll
        for (int j = 0; j < 4; j++) acc[i][j] += vmv[i] * kkv[j];
      if (t < 16) { ks[0] += kkv[0]; ks[1] += kkv[1]; ks[2] += kkv[2]; ks[3] += kkv[3]; }
    }
  }
  float* o = kvp + ((size_t)bh*NCH_ + blockIdx.y) * 4096;
  #pragma unroll
  for (int i = 0; i < 4; i++) {
    float4 wv = {acc[i][0], acc[i][1], acc[i][2], acc[i][3]};
    *(float4*)(o + (m0 + i)*64 + d0) = wv;
  }
  if (t < 16) {
    float* ko = ksp + ((size_t)bh*NCH_ + blockIdx.y) * 64;
    #pragma unroll
    for (int j = 0; j < 4; j++) ko[d0 + j] = ks[j];
  }
}

// ---------------- KV stage 2: reduce over chunks ----------------
__global__ __launch_bounds__(256) void kv_reduce(
    const float* __restrict__ kvp, const float* __restrict__ ksp,
    float* __restrict__ kv, float* __restrict__ ksum)
{
  const int bh = blockIdx.x;
  const int i = blockIdx.y * 256 + threadIdx.x;
  float s = 0.f;
  #pragma unroll
  for (int c = 0; c < NCH_; c++) s += kvp[((size_t)bh*NCH_ + c)*4096 + i];
  kv[(size_t)bh*4096 + i] = s;
  if (blockIdx.y == 0 && threadIdx.x < 64) {
    float q = 0.f;
    #pragma unroll
    for (int c = 0; c < NCH_; c++) q += ksp[((size_t)bh*NCH_ + c)*64 + threadIdx.x];
    ksum[bh*64 + threadIdx.x] = q;
  }
}

// ---------------- attn: a[l,h,m] = Z * sum_d Q[l,h,d]*KV[h,m,d] (MFMA) ----------------
__global__ __launch_bounds__(256) void attn_av(
    const u16* __restrict__ qkv, const float* __restrict__ kv,
    const float* __restrict__ ksum, u16* __restrict__ ab)
{
  __shared__ alignas(16) u16 sQ[128*72];
  __shared__ alignas(16) u16 sKV[64*72];
  __shared__ float sKs[64];
  __shared__ float sZ[128];
  const int bh = blockIdx.x;
  const int b = bh / H_, h = bh % H_;
  const int l0 = blockIdx.y * 128;
  const int t = threadIdx.x;
  const int lane = t & 63;
  const int w = t >> 6;
  // stage KV (f32 -> bf16)
  for (int i = t; i < 4096; i += 256)
    sKV[(i >> 6)*72 + (i & 63)] = f2b(kv[(size_t)bh*4096 + i]);
  if (t < 64) sKs[t] = ksum[bh*64 + t];
  // stage Q (bf16, from fused qkv)
  #pragma unroll
  for (int r = 0; r < 4; r++) {
    int idx = r*256 + t;
    int s = idx >> 3;
    int c = (idx & 7) * 8;
    *(uint4*)(sQ + s*72 + c) =
        *(const uint4*)(qkv + ((size_t)(b*L_ + l0 + s)) * QLD_ + h*DH_ + c);
  }
  __syncthreads();
  // Z per row: 2 threads/row
  {
    int row = t >> 1, half = t & 1;
    float zd = 0.f;
    #pragma unroll
    for (int ch = 0; ch < 4; ch++) {
      bf16x8 qv = *(const bf16x8*)(sQ + row*72 + half*32 + ch*8);
      #pragma unroll
      for (int j = 0; j < 8; j++) zd += (float)qv[j] * sKs[half*32 + ch*8 + j];
    }
    zd += __shfl_xor(zd, 1, 64);
    if (half == 0) sZ[row] = 1.f / (zd + ATT_EPS_);
  }
  // MFMA: wave w -> rows w*32..w*32+31, cols 0..63
  const int lr = lane & 15, lk = (lane >> 4) * 8;
  f32x4 acc[2][4];
  #pragma unroll
  for (int m = 0; m < 2; m++)
    #pragma unroll
    for (int n = 0; n < 4; n++) acc[m][n] = (f32x4){0.f,0.f,0.f,0.f};
  #pragma unroll
  for (int kk = 0; kk < 2; kk++) {
    bf16x8 af[2], bv[4];
    #pragma unroll
    for (int m = 0; m < 2; m++) af[m] = *(const bf16x8*)(sQ + (w*32 + m*16 + lr)*72 + kk*32 + lk);
    #pragma unroll
    for (int n = 0; n < 4; n++) bv[n] = *(const bf16x8*)(sKV + (n*16 + lr)*72 + kk*32 + lk);
    #pragma unroll
    for (int m = 0; m < 2; m++)
      #pragma unroll
      for (int n = 0; n < 4; n++)
        acc[m][n] = __builtin_amdgcn_mfma_f32_16x16x32_bf16(af[m], bv[n], acc[m][n], 0, 0, 0);
  }
  __syncthreads();   // sZ visible
  #pragma unroll
  for (int m = 0; m < 2; m++) {
    const int row_l = w*32 + m*16 + (lane >> 4) * 4;
    #pragma unroll
    for (int n = 0; n < 4; n++) {
      const int col = n*16 + lr;
      #pragma unroll
      for (int r = 0; r < 4; r++) {
        float v = acc[m][n][r] * sZ[row_l + r];
        ab[((size_t)(b*L_ + l0 + row_l + r)) * DM_ + h*DH_ + col] = f2b(v);
      }
    }
  }
}

// ---------------- final copy ----------------
__global__ __launch_bounds__(256) void copyf4(const float4* __restrict__ in,
                                              float4* __restrict__ out, int n4) {
  int i = blockIdx.x * 256 + threadIdx.x;
  if (i < n4) out[i] = in[i];
}

extern "C" void kernel_launch(void* const* d_in, const int* in_sizes, int n_in,
                              void* d_out, int out_size, void* d_ws, size_t ws_size,
                              hipStream_t stream)
{
  const int*   ids  = (const int*)d_in[0];
  const float* mask = (const float*)d_in[1];
  const int*   tts  = (const int*)d_in[2];
  const float* we   = (const float*)d_in[3];
  const float* pe   = (const float*)d_in[4];
  const float* te   = (const float*)d_in[5];
  const float* elw  = (const float*)d_in[6];
  const float* elb  = (const float*)d_in[7];
  const float* Wq   = (const float*)d_in[8];
  const float* bq   = (const float*)d_in[9];
  const float* Wk   = (const float*)d_in[10];
  const float* bk   = (const float*)d_in[11];
  const float* Wv   = (const float*)d_in[12];
  const float* bv   = (const float*)d_in[13];
  const float* Wo   = (const float*)d_in[14];
  const float* bo   = (const float*)d_in[15];
  const float* l1w  = (const float*)d_in[16];
  const float* l1b  = (const float*)d_in[17];
  const float* W1   = (const float*)d_in[18];
  const float* b1   = (const float*)d_in[19];
  const float* W2   = (const float*)d_in[20];
  const float* b2   = (const float*)d_in[21];
  const float* l2w  = (const float*)d_in[22];
  const float* l2b  = (const float*)d_in[23];

  char* p = (char*)d_ws;
  auto alloc = [&](size_t n) -> char* {
    char* r = p; p += (n + 255) & ~(size_t)255; return r;
  };
  const size_t SQ = (size_t)NL_ * DM_ * DM_;
  const size_t SF = (size_t)NL_ * DFF_ * DM_;
  u16*  wqkvb = (u16*)alloc((size_t)NL_ * QLD_ * DM_ * 2);
  u16*  wob   = (u16*)alloc(SQ * 2);
  u16*  w1b   = (u16*)alloc(SF * 2);
  u16*  w2b   = (u16*)alloc(SF * 2);
  float* bqkv = (float*)alloc((size_t)NL_ * QLD_ * 4);
  float* x32  = (float*)alloc((size_t)M_ * DM_ * 4);
  u16*  t16   = (u16*)alloc((size_t)M_ * DM_ * 2);
  u16*  xb    = (u16*)alloc((size_t)M_ * DM_ * 2);
  u16*  qkv   = (u16*)alloc((size_t)M_ * QLD_ * 2);
  u16*  abuf  = (u16*)alloc((size_t)M_ * DM_ * 2);
  u16*  ybuf  = (u16*)alloc((size_t)M_ * DFF_ * 2);
  float* kvb  = (float*)alloc((size_t)(B_*H_*DH_*DH_ + B_*H_*DH_) * 4);
  float* ksm  = kvb + (size_t)B_*H_*DH_*DH_;
  float* ksp  = (float*)alloc((size_t)B_*H_*NCH_*DH_ * 4);
  float* kvp  = (float*)alloc((size_t)B_*H_*NCH_*DH_*DH_ * 4);   // 6.3 MB partials

  const int nq4 = (int)(SQ/4);
  cvt_bf16_qkv<<<(nq4+255)/256, 256, 0, stream>>>(Wq, wqkvb, 0);
  cvt_bf16_qkv<<<(nq4+255)/256, 256, 0, stream>>>(Wk, wqkvb, DM_);
  cvt_bf16_qkv<<<(nq4+255)/256, 256, 0, stream>>>(Wv, wqkvb, 2*DM_);
  cvt_bf16<<<nq4/256, 256, 0, stream>>>(Wo, wob, nq4);
  cvt_bf16<<<(int)(SF/4/256), 256, 0, stream>>>(W1, w1b, (int)(SF/4));
  cvt_bf16<<<(int)(SF/4/256), 256, 0, stream>>>(W2, w2b, (int)(SF/4));
  fuse_bias<<<(NL_*QLD_+255)/256, 256, 0, stream>>>(bq, bk, bv, bqkv);

  embed_ln<<<M_/4, 256, 0, stream>>>(ids, tts, we, pe, te, elw, elb, x32, xb);

  for (int il = 0; il < NL_; ++il) {
    const u16* wqkv = wqkvb + (size_t)il * QLD_ * DM_;
    const u16* wo = wob + (size_t)il * DM_ * DM_;
    const u16* w1 = w1b + (size_t)il * DFF_ * DM_;
    const u16* w2 = w2b + (size_t)il * DFF_ * DM_;

    gemm_gl<4><<<dim3(M_/128, QLD_/128), 256, 0, stream>>>(
        xb, wqkv, bqkv + (size_t)il*QLD_, qkv, M_, QLD_, DM_, QLD_);

    kv_part<<<dim3(B_*H_, NCH_), 256, 0, stream>>>(qkv, mask, kvp, ksp);
    kv_reduce<<<dim3(B_*H_, 16), 256, 0, stream>>>(kvp, ksp, kvb, ksm);
    attn_av<<<dim3(B_*H_, L_/128), 256, 0, stream>>>(qkv, kvb, ksm, abuf);

    gemm_n64<<<dim3(M_/128, DM_/64), 256, 0, stream>>>(
        abuf, wo, bo + (size_t)il*DM_, t16, M_, DM_, DM_, DM_);
    ln_res<<<M_/4, 256, 0, stream>>>(x32, t16, l1w + (size_t)il*DM_, l1b + (size_t)il*DM_, xb, LN_EPS_);

    gemm_m2<<<dim3(M_/256, DFF_/128), 256, 0, stream>>>(
        xb, w1, b1 + (size_t)il*DFF_, ybuf, M_, DFF_, DM_, DFF_);
    gemm_n64<<<dim3(M_/128, DM_/64), 256, 0, stream>>>(
        ybuf, w2, b2 + (size_t)il*DM_, t16, M_, DM_, DFF_, DM_);
    ln_res<<<M_/4, 256, 0, stream>>>(x32, t16, l2w + (size_t)il*DM_, l2b + (size_t)il*DM_, xb, LN_EPS_);
  }

  copyf4<<<(M_*DM_/4)/256, 256, 0, stream>>>((const float4*)x32, (float4*)d_out, M_*DM_/4);
}

// Round 16
// 3093.121 us; speedup vs baseline: 1.2136x; 1.2136x over previous
//
#include <hip/hip_runtime.h>
#include <math.h>

#define B_   4
#define L_   2048
#define H_   12
#define DH_  64
#define DM_  768
#define DFF_ 3072
#define NL_  12
#define M_   (B_*L_)
#define NCH_ 8               // kv partial chunks (each block covers 256 seq rows)
#define QLD_ 2304            // fused QKV row stride
#define LN_EPS_  1e-5f
#define EMB_EPS_ 1e-12f
#define ATT_EPS_ 1e-6f

typedef unsigned short u16;
typedef __bf16 bf16x8 __attribute__((ext_vector_type(8)));
typedef float  f32x4  __attribute__((ext_vector_type(4)));

__device__ __forceinline__ u16 f2b(float f) {
  unsigned u = __builtin_bit_cast(unsigned, f);
  u += 0x7fffu + ((u >> 16) & 1u);
  return (u16)(u >> 16);
}
__device__ __forceinline__ float b2f(u16 s) {
  return __builtin_bit_cast(float, (unsigned)((unsigned)s << 16));
}
__device__ __forceinline__ float wredsum(float v) {
  #pragma unroll
  for (int o = 32; o > 0; o >>= 1) v += __shfl_xor(v, o, 64);
  return v;
}
// async global->LDS, 16B per lane; lds dest is wave-uniform base + lane*16
__device__ __forceinline__ void gld16(const void* g, void* l) {
  __builtin_amdgcn_global_load_lds(
      (const __attribute__((address_space(1))) void*)g,
      (__attribute__((address_space(3))) void*)l, 16, 0, 0);
}

// ---------------- weight f32 -> bf16 (layout-preserving) ----------------
__global__ __launch_bounds__(256) void cvt_bf16(const float* __restrict__ in,
                                                u16* __restrict__ out, int n4) {
  int i = blockIdx.x * 256 + threadIdx.x;
  if (i >= n4) return;
  float4 f = ((const float4*)in)[i];
  ushort4 o;
  o.x = f2b(f.x); o.y = f2b(f.y); o.z = f2b(f.z); o.w = f2b(f.w);
  ((ushort4*)out)[i] = o;
}

// ---------------- weight f32 -> bf16 into fused [NL][2304][768] at row offset ro ----------------
__global__ __launch_bounds__(256) void cvt_bf16_qkv(const float* __restrict__ in,
                                                    u16* __restrict__ out, int ro) {
  int i = blockIdx.x * 256 + threadIdx.x;   // over NL*768*768/4
  if (i >= NL_*DM_*DM_/4) return;
  int row = i / 192;            // global row (l*768 + r), 192 float4 per row
  int c4  = (i % 192) * 4;
  int l = row / DM_, r = row % DM_;
  float4 f = ((const float4*)in)[i];
  ushort4 o;
  o.x = f2b(f.x); o.y = f2b(f.y); o.z = f2b(f.z); o.w = f2b(f.w);
  *(ushort4*)(out + ((size_t)l*QLD_ + ro + r)*DM_ + c4) = o;
}

// ---------------- fused bias [NL][2304] ----------------
__global__ __launch_bounds__(256) void fuse_bias(const float* __restrict__ bq,
    const float* __restrict__ bk, const float* __restrict__ bv, float* __restrict__ out) {
  int i = blockIdx.x * 256 + threadIdx.x;
  if (i >= NL_*QLD_) return;
  int l = i / QLD_, r = i % QLD_;
  float v = r < DM_ ? bq[l*DM_ + r] : r < 2*DM_ ? bk[l*DM_ + r - DM_] : bv[l*DM_ + r - 2*DM_];
  out[i] = v;
}

// ---------------- embedding + LN ----------------
__global__ __launch_bounds__(256) void embed_ln(
    const int* __restrict__ ids, const int* __restrict__ tts,
    const float* __restrict__ we, const float* __restrict__ pe,
    const float* __restrict__ te, const float* __restrict__ lw,
    const float* __restrict__ lb, float* __restrict__ x32, u16* __restrict__ xb)
{
  int row  = blockIdx.x * 4 + (threadIdx.x >> 6);
  int lane = threadIdx.x & 63;
  int l  = row & (L_ - 1);
  int id = ids[row];
  int tt = tts[row];
  const float* wr = we + (size_t)id * DM_;
  const float* pr = pe + (size_t)l  * DM_;
  const float* tr = te + (size_t)tt * DM_;
  float v[12]; float s = 0.f;
  #pragma unroll
  for (int j = 0; j < 12; j++) { int c = j*64 + lane; v[j] = wr[c] + pr[c] + tr[c]; s += v[j]; }
  s = wredsum(s);
  float m = s * (1.f/768.f);
  float q = 0.f;
  #pragma unroll
  for (int j = 0; j < 12; j++) { float d = v[j] - m; q += d*d; }
  q = wredsum(q);
  float rs = rsqrtf(q * (1.f/768.f) + EMB_EPS_);
  float* xo = x32 + (size_t)row * DM_;
  u16*   bo = xb  + (size_t)row * DM_;
  #pragma unroll
  for (int j = 0; j < 12; j++) {
    int c = j*64 + lane;
    float o = (v[j] - m) * rs * lw[c] + lb[c];
    xo[c] = o; bo[c] = f2b(o);
  }
}

// ---------------- residual + LN (x32 f32 master; t is bf16) ----------------
__global__ __launch_bounds__(256) void ln_res(
    float* __restrict__ x32, const u16* __restrict__ t16,
    const float* __restrict__ lw, const float* __restrict__ lb,
    u16* __restrict__ xb, float eps)
{
  int row  = blockIdx.x * 4 + (threadIdx.x >> 6);
  int lane = threadIdx.x & 63;
  float* xr = x32 + (size_t)row * DM_;
  const u16* tr = t16 + (size_t)row * DM_;
  float v[12]; float s = 0.f;
  #pragma unroll
  for (int j = 0; j < 12; j++) { int c = j*64 + lane; v[j] = xr[c] + b2f(tr[c]); s += v[j]; }
  s = wredsum(s);
  float m = s * (1.f/768.f);
  float q = 0.f;
  #pragma unroll
  for (int j = 0; j < 12; j++) { float d = v[j] - m; q += d*d; }
  q = wredsum(q);
  float rs = rsqrtf(q * (1.f/768.f) + eps);
  u16* bo = xb + (size_t)row * DM_;
  #pragma unroll
  for (int j = 0; j < 12; j++) {
    int c = j*64 + lane;
    float o = (v[j] - m) * rs * lw[c] + lb[c];
    xr[c] = o; bo[c] = f2b(o);
  }
}

// ---------------- GEMM (all shapes): BM=128, BN=64, BK=64, bf16 out + bias ----------------
// Highest-occupancy member of the family (24 KB LDS, ~48-70 VGPR -> ~12 blocks/CU);
// W2 evidence: this shape sustains ~19 TB/s LDS-staging vs 8.4 TB/s for the 128x128 tile.
// Both-sides XOR swizzle: linear gld16 dest, pre-swizzled global source group
// (lane&7)^(row&7), read group (kk*4+g)^(lr&7).
// EPI: 0 = bf16 out, 2 = gelu(erf)->bf16, 4 = QKV fused (elu+1 on cols<1536)
template<int EPI>
__global__ __launch_bounds__(256)
void gemm_n64(const u16* __restrict__ A, const u16* __restrict__ Bw,
              const float* __restrict__ bias, u16* __restrict__ Ct,
              int M, int N, int K, int ldc)
{
  __shared__ alignas(16) u16 sA[128*64];
  __shared__ alignas(16) u16 sB[64*64];
  const int tid  = threadIdx.x;
  const int lane = tid & 63;
  const int w    = tid >> 6;
  const int row0 = blockIdx.x * 128;
  const int col0 = blockIdx.y * 64;
  const int lr = lane & 15;
  const int g  = lane >> 4;
  const int srow = lane >> 3;
  const int acol = (((lane & 7) ^ srow) * 8);

  f32x4 acc[2][4];
  #pragma unroll
  for (int i = 0; i < 2; i++)
    #pragma unroll
    for (int j = 0; j < 4; j++) acc[i][j] = (f32x4){0.f,0.f,0.f,0.f};

  const u16* ApA = A  + (size_t)(row0)*K;
  const u16* BpB = Bw + (size_t)(col0)*K;

  for (int kt = 0; kt < K; kt += 64) {
    #pragma unroll
    for (int j = 0; j < 4; j++)
      gld16(ApA + (size_t)(w*32 + j*8 + srow)*K + kt + acol, sA + (w*32 + j*8)*64);
    #pragma unroll
    for (int j = 0; j < 2; j++)
      gld16(BpB + (size_t)(w*16 + j*8 + srow)*K + kt + acol, sB + (w*16 + j*8)*64);
    __syncthreads();
    #pragma unroll
    for (int kk = 0; kk < 2; kk++) {
      const int gg = ((kk*4 + g) ^ (lr & 7)) * 8;
      bf16x8 af[2], bv[4];
      #pragma unroll
      for (int m = 0; m < 2; m++) af[m] = *(const bf16x8*)(sA + (w*32 + m*16 + lr)*64 + gg);
      #pragma unroll
      for (int n = 0; n < 4; n++) bv[n] = *(const bf16x8*)(sB + (n*16 + lr)*64 + gg);
      #pragma unroll
      for (int m = 0; m < 2; m++)
        #pragma unroll
        for (int n = 0; n < 4; n++)
          acc[m][n] = __builtin_amdgcn_mfma_f32_16x16x32_bf16(af[m], bv[n], acc[m][n], 0, 0, 0);
    }
    __syncthreads();
  }

  #pragma unroll
  for (int m = 0; m < 2; m++) {
    const int row_b = row0 + w*32 + m*16 + (lane >> 4) * 4;
    #pragma unroll
    for (int n = 0; n < 4; n++) {
      const int col = col0 + n*16 + lr;
      const float bvb = bias[col];
      #pragma unroll
      for (int r = 0; r < 4; r++) {
        float v = acc[m][n][r] + bvb;
        if constexpr (EPI == 4) { if (col < 2*DM_) v = v > 0.f ? v + 1.f : __expf(v); }
        if constexpr (EPI == 2) v = 0.5f * v * (1.f + erff(v * 0.70710678118654752f));
        Ct[(size_t)(row_b + r) * ldc + col] = f2b(v);
      }
    }
  }
}

// ---------------- KV stage 1: per-(bh, 256-seq-chunk) partial outer product ----------------
__global__ __launch_bounds__(256) void kv_part(
    const u16* __restrict__ qkv, const float* __restrict__ mask,
    float* __restrict__ kvp, float* __restrict__ ksp)
{
  __shared__ float sK[64*64];
  __shared__ float sV[64*64];
  const int bh = blockIdx.x;
  const int b = bh / H_, h = bh % H_;
  const int s0 = blockIdx.y * 256;
  const int t = threadIdx.x;
  const u16* kb = qkv + DM_;
  const u16* vb = qkv + 2*DM_;
  const int m0 = (t >> 4) * 4;
  const int d0 = (t & 15) * 4;
  float acc[4][4] = {{0.f}};
  float ks[4] = {0.f, 0.f, 0.f, 0.f};

  for (int cc = 0; cc < 4; cc++) {
    __syncthreads();   // previous sub-chunk's reads done before overwrite
    #pragma unroll
    for (int r = 0; r < 2; r++) {
      int idx = r*256 + t;
      int sr = idx >> 3;
      int c  = (idx & 7) * 8;
      int sg = s0 + cc*64 + sr;
      size_t base = ((size_t)(b*L_ + sg)) * QLD_ + h*DH_ + c;
      uint4 kk = *(const uint4*)(kb + base);
      uint4 vv = *(const uint4*)(vb + base);
      float mk = mask[b*L_ + sg];
      const u16* kp = (const u16*)&kk;
      const u16* vp = (const u16*)&vv;
      #pragma unroll
      for (int j = 0; j < 8; j++) {
        sK[sr*64 + c + j] = b2f(kp[j]) * mk;
        sV[sr*64 + c + j] = b2f(vp[j]);
      }
    }
    __syncthreads();
    for (int s = 0; s < 64; s++) {
      float4 vm = *(const float4*)(sV + s*64 + m0);
      float4 kk = *(const float4*)(sK + s*64 + d0);
      float vmv[4] = {vm.x, vm.y, vm.z, vm.w};
      float kkv[4] = {kk.x, kk.y, kk.z, kk.w};
      #pragma unroll
      for (int i = 0; i < 4; i++)
        #pragma unroll
        for (int j = 0; j < 4; j++) acc[i][j] += vmv[i] * kkv[j];
      if (t < 16) { ks[0] += kkv[0]; ks[1] += kkv[1]; ks[2] += kkv[2]; ks[3] += kkv[3]; }
    }
  }
  float* o = kvp + ((size_t)bh*NCH_ + blockIdx.y) * 4096;
  #pragma unroll
  for (int i = 0; i < 4; i++) {
    float4 wv = {acc[i][0], acc[i][1], acc[i][2], acc[i][3]};
    *(float4*)(o + (m0 + i)*64 + d0) = wv;
  }
  if (t < 16) {
    float* ko = ksp + ((size_t)bh*NCH_ + blockIdx.y) * 64;
    #pragma unroll
    for (int j = 0; j < 4; j++) ko[d0 + j] = ks[j];
  }
}

// ---------------- KV stage 2: reduce over chunks ----------------
__global__ __launch_bounds__(256) void kv_reduce(
    const float* __restrict__ kvp, const float* __restrict__ ksp,
    float* __restrict__ kv, float* __restrict__ ksum)
{
  const int bh = blockIdx.x;
  const int i = blockIdx.y * 256 + threadIdx.x;
  float s = 0.f;
  #pragma unroll
  for (int c = 0; c < NCH_; c++) s += kvp[((size_t)bh*NCH_ + c)*4096 + i];
  kv[(size_t)bh*4096 + i] = s;
  if (blockIdx.y == 0 && threadIdx.x < 64) {
    float q = 0.f;
    #pragma unroll
    for (int c = 0; c < NCH_; c++) q += ksp[((size_t)bh*NCH_ + c)*64 + threadIdx.x];
    ksum[bh*64 + threadIdx.x] = q;
  }
}

// ---------------- attn: a[l,h,m] = Z * sum_d Q[l,h,d]*KV[h,m,d] (MFMA) ----------------
__global__ __launch_bounds__(256) void attn_av(
    const u16* __restrict__ qkv, const float* __restrict__ kv,
    const float* __restrict__ ksum, u16* __restrict__ ab)
{
  __shared__ alignas(16) u16 sQ[128*72];
  __shared__ alignas(16) u16 sKV[64*72];
  __shared__ float sKs[64];
  __shared__ float sZ[128];
  const int bh = blockIdx.x;
  const int b = bh / H_, h = bh % H_;
  const int l0 = blockIdx.y * 128;
  const int t = threadIdx.x;
  const int lane = t & 63;
  const int w = t >> 6;
  // stage KV (f32 -> bf16)
  for (int i = t; i < 4096; i += 256)
    sKV[(i >> 6)*72 + (i & 63)] = f2b(kv[(size_t)bh*4096 + i]);
  if (t < 64) sKs[t] = ksum[bh*64 + t];
  // stage Q (bf16, from fused qkv)
  #pragma unroll
  for (int r = 0; r < 4; r++) {
    int idx = r*256 + t;
    int s = idx >> 3;
    int c = (idx & 7) * 8;
    *(uint4*)(sQ + s*72 + c) =
        *(const uint4*)(qkv + ((size_t)(b*L_ + l0 + s)) * QLD_ + h*DH_ + c);
  }
  __syncthreads();
  // Z per row: 2 threads/row
  {
    int row = t >> 1, half = t & 1;
    float zd = 0.f;
    #pragma unroll
    for (int ch = 0; ch < 4; ch++) {
      bf16x8 qv = *(const bf16x8*)(sQ + row*72 + half*32 + ch*8);
      #pragma unroll
      for (int j = 0; j < 8; j++) zd += (float)qv[j] * sKs[half*32 + ch*8 + j];
    }
    zd += __shfl_xor(zd, 1, 64);
    if (half == 0) sZ[row] = 1.f / (zd + ATT_EPS_);
  }
  // MFMA: wave w -> rows w*32..w*32+31, cols 0..63
  const int lr = lane & 15, lk = (lane >> 4) * 8;
  f32x4 acc[2][4];
  #pragma unroll
  for (int m = 0; m < 2; m++)
    #pragma unroll
    for (int n = 0; n < 4; n++) acc[m][n] = (f32x4){0.f,0.f,0.f,0.f};
  #pragma unroll
  for (int kk = 0; kk < 2; kk++) {
    bf16x8 af[2], bv[4];
    #pragma unroll
    for (int m = 0; m < 2; m++) af[m] = *(const bf16x8*)(sQ + (w*32 + m*16 + lr)*72 + kk*32 + lk);
    #pragma unroll
    for (int n = 0; n < 4; n++) bv[n] = *(const bf16x8*)(sKV + (n*16 + lr)*72 + kk*32 + lk);
    #pragma unroll
    for (int m = 0; m < 2; m++)
      #pragma unroll
      for (int n = 0; n < 4; n++)
        acc[m][n] = __builtin_amdgcn_mfma_f32_16x16x32_bf16(af[m], bv[n], acc[m][n], 0, 0, 0);
  }
  __syncthreads();   // sZ visible
  #pragma unroll
  for (int m = 0; m < 2; m++) {
    const int row_l = w*32 + m*16 + (lane >> 4) * 4;
    #pragma unroll
    for (int n = 0; n < 4; n++) {
      const int col = n*16 + lr;
      #pragma unroll
      for (int r = 0; r < 4; r++) {
        float v = acc[m][n][r] * sZ[row_l + r];
        ab[((size_t)(b*L_ + l0 + row_l + r)) * DM_ + h*DH_ + col] = f2b(v);
      }
    }
  }
}

// ---------------- final copy ----------------
__global__ __launch_bounds__(256) void copyf4(const float4* __restrict__ in,
                                              float4* __restrict__ out, int n4) {
  int i = blockIdx.x * 256 + threadIdx.x;
  if (i < n4) out[i] = in[i];
}

extern "C" void kernel_launch(void* const* d_in, const int* in_sizes, int n_in,
                              void* d_out, int out_size, void* d_ws, size_t ws_size,
                              hipStream_t stream)
{
  const int*   ids  = (const int*)d_in[0];
  const float* mask = (const float*)d_in[1];
  const int*   tts  = (const int*)d_in[2];
  const float* we   = (const float*)d_in[3];
  const float* pe   = (const float*)d_in[4];
  const float* te   = (const float*)d_in[5];
  const float* elw  = (const float*)d_in[6];
  const float* elb  = (const float*)d_in[7];
  const float* Wq   = (const float*)d_in[8];
  const float* bq   = (const float*)d_in[9];
  const float* Wk   = (const float*)d_in[10];
  const float* bk   = (const float*)d_in[11];
  const float* Wv   = (const float*)d_in[12];
  const float* bv   = (const float*)d_in[13];
  const float* Wo   = (const float*)d_in[14];
  const float* bo   = (const float*)d_in[15];
  const float* l1w  = (const float*)d_in[16];
  const float* l1b  = (const float*)d_in[17];
  const float* W1   = (const float*)d_in[18];
  const float* b1   = (const float*)d_in[19];
  const float* W2   = (const float*)d_in[20];
  const float* b2   = (const float*)d_in[21];
  const float* l2w  = (const float*)d_in[22];
  const float* l2b  = (const float*)d_in[23];

  char* p = (char*)d_ws;
  auto alloc = [&](size_t n) -> char* {
    char* r = p; p += (n + 255) & ~(size_t)255; return r;
  };
  const size_t SQ = (size_t)NL_ * DM_ * DM_;
  const size_t SF = (size_t)NL_ * DFF_ * DM_;
  u16*  wqkvb = (u16*)alloc((size_t)NL_ * QLD_ * DM_ * 2);
  u16*  wob   = (u16*)alloc(SQ * 2);
  u16*  w1b   = (u16*)alloc(SF * 2);
  u16*  w2b   = (u16*)alloc(SF * 2);
  float* bqkv = (float*)alloc((size_t)NL_ * QLD_ * 4);
  float* x32  = (float*)alloc((size_t)M_ * DM_ * 4);
  u16*  t16   = (u16*)alloc((size_t)M_ * DM_ * 2);
  u16*  xb    = (u16*)alloc((size_t)M_ * DM_ * 2);
  u16*  qkv   = (u16*)alloc((size_t)M_ * QLD_ * 2);
  u16*  abuf  = (u16*)alloc((size_t)M_ * DM_ * 2);
  u16*  ybuf  = (u16*)alloc((size_t)M_ * DFF_ * 2);
  float* kvb  = (float*)alloc((size_t)(B_*H_*DH_*DH_ + B_*H_*DH_) * 4);
  float* ksm  = kvb + (size_t)B_*H_*DH_*DH_;
  float* ksp  = (float*)alloc((size_t)B_*H_*NCH_*DH_ * 4);
  float* kvp  = (float*)alloc((size_t)B_*H_*NCH_*DH_*DH_ * 4);   // 6.3 MB partials

  const int nq4 = (int)(SQ/4);
  cvt_bf16_qkv<<<(nq4+255)/256, 256, 0, stream>>>(Wq, wqkvb, 0);
  cvt_bf16_qkv<<<(nq4+255)/256, 256, 0, stream>>>(Wk, wqkvb, DM_);
  cvt_bf16_qkv<<<(nq4+255)/256, 256, 0, stream>>>(Wv, wqkvb, 2*DM_);
  cvt_bf16<<<nq4/256, 256, 0, stream>>>(Wo, wob, nq4);
  cvt_bf16<<<(int)(SF/4/256), 256, 0, stream>>>(W1, w1b, (int)(SF/4));
  cvt_bf16<<<(int)(SF/4/256), 256, 0, stream>>>(W2, w2b, (int)(SF/4));
  fuse_bias<<<(NL_*QLD_+255)/256, 256, 0, stream>>>(bq, bk, bv, bqkv);

  embed_ln<<<M_/4, 256, 0, stream>>>(ids, tts, we, pe, te, elw, elb, x32, xb);

  for (int il = 0; il < NL_; ++il) {
    const u16* wqkv = wqkvb + (size_t)il * QLD_ * DM_;
    const u16* wo = wob + (size_t)il * DM_ * DM_;
    const u16* w1 = w1b + (size_t)il * DFF_ * DM_;
    const u16* w2 = w2b + (size_t)il * DFF_ * DM_;

    gemm_n64<4><<<dim3(M_/128, QLD_/64), 256, 0, stream>>>(
        xb, wqkv, bqkv + (size_t)il*QLD_, qkv, M_, QLD_, DM_, QLD_);

    kv_part<<<dim3(B_*H_, NCH_), 256, 0, stream>>>(qkv, mask, kvp, ksp);
    kv_reduce<<<dim3(B_*H_, 16), 256, 0, stream>>>(kvp, ksp, kvb, ksm);
    attn_av<<<dim3(B_*H_, L_/128), 256, 0, stream>>>(qkv, kvb, ksm, abuf);

    gemm_n64<0><<<dim3(M_/128, DM_/64), 256, 0, stream>>>(
        abuf, wo, bo + (size_t)il*DM_, t16, M_, DM_, DM_, DM_);
    ln_res<<<M_/4, 256, 0, stream>>>(x32, t16, l1w + (size_t)il*DM_, l1b + (size_t)il*DM_, xb, LN_EPS_);

    gemm_n64<2><<<dim3(M_/128, DFF_/64), 256, 0, stream>>>(
        xb, w1, b1 + (size_t)il*DFF_, ybuf, M_, DFF_, DM_, DFF_);
    gemm_n64<0><<<dim3(M_/128, DM_/64), 256, 0, stream>>>(
        ybuf, w2, b2 + (size_t)il*DM_, t16, M_, DM_, DFF_, DM_);
    ln_res<<<M_/4, 256, 0, stream>>>(x32, t16, l2w + (size_t)il*DM_, l2b + (size_t)il*DM_, xb, LN_EPS_);
  }

  copyf4<<<(M_*DM_/4)/256, 256, 0, stream>>>((const float4*)x32, (float4*)d_out, M_*DM_/4);
}

// Round 17
// 3064.864 us; speedup vs baseline: 1.2248x; 1.0092x over previous
//
#include <hip/hip_runtime.h>
#include <math.h>

#define B_   4
#define L_   2048
#define H_   12
#define DH_  64
#define DM_  768
#define DFF_ 3072
#define NL_  12
#define M_   (B_*L_)
#define NCH_ 8               // kv partial chunks (each block covers 256 seq rows)
#define QLD_ 2304            // fused QKV row stride
#define LN_EPS_  1e-5f
#define EMB_EPS_ 1e-12f
#define ATT_EPS_ 1e-6f

typedef unsigned short u16;
typedef __bf16 bf16x8 __attribute__((ext_vector_type(8)));
typedef float  f32x4  __attribute__((ext_vector_type(4)));

__device__ __forceinline__ u16 f2b(float f) {
  unsigned u = __builtin_bit_cast(unsigned, f);
  u += 0x7fffu + ((u >> 16) & 1u);
  return (u16)(u >> 16);
}
__device__ __forceinline__ float b2f(u16 s) {
  return __builtin_bit_cast(float, (unsigned)((unsigned)s << 16));
}
__device__ __forceinline__ float wredsum(float v) {
  #pragma unroll
  for (int o = 32; o > 0; o >>= 1) v += __shfl_xor(v, o, 64);
  return v;
}
// async global->LDS, 16B per lane; lds dest is wave-uniform base + lane*16
__device__ __forceinline__ void gld16(const void* g, void* l) {
  __builtin_amdgcn_global_load_lds(
      (const __attribute__((address_space(1))) void*)g,
      (__attribute__((address_space(3))) void*)l, 16, 0, 0);
}

// ---------------- weight f32 -> bf16 (layout-preserving) ----------------
__global__ __launch_bounds__(256) void cvt_bf16(const float* __restrict__ in,
                                                u16* __restrict__ out, int n4) {
  int i = blockIdx.x * 256 + threadIdx.x;
  if (i >= n4) return;
  float4 f = ((const float4*)in)[i];
  ushort4 o;
  o.x = f2b(f.x); o.y = f2b(f.y); o.z = f2b(f.z); o.w = f2b(f.w);
  ((ushort4*)out)[i] = o;
}

// ---------------- weight f32 -> bf16 into fused [NL][2304][768] at row offset ro ----------------
__global__ __launch_bounds__(256) void cvt_bf16_qkv(const float* __restrict__ in,
                                                    u16* __restrict__ out, int ro) {
  int i = blockIdx.x * 256 + threadIdx.x;   // over NL*768*768/4
  if (i >= NL_*DM_*DM_/4) return;
  int row = i / 192;            // global row (l*768 + r), 192 float4 per row
  int c4  = (i % 192) * 4;
  int l = row / DM_, r = row % DM_;
  float4 f = ((const float4*)in)[i];
  ushort4 o;
  o.x = f2b(f.x); o.y = f2b(f.y); o.z = f2b(f.z); o.w = f2b(f.w);
  *(ushort4*)(out + ((size_t)l*QLD_ + ro + r)*DM_ + c4) = o;
}

// ---------------- fused bias [NL][2304] ----------------
__global__ __launch_bounds__(256) void fuse_bias(const float* __restrict__ bq,
    const float* __restrict__ bk, const float* __restrict__ bv, float* __restrict__ out) {
  int i = blockIdx.x * 256 + threadIdx.x;
  if (i >= NL_*QLD_) return;
  int l = i / QLD_, r = i % QLD_;
  float v = r < DM_ ? bq[l*DM_ + r] : r < 2*DM_ ? bk[l*DM_ + r - DM_] : bv[l*DM_ + r - 2*DM_];
  out[i] = v;
}

// ---------------- embedding + LN ----------------
__global__ __launch_bounds__(256) void embed_ln(
    const int* __restrict__ ids, const int* __restrict__ tts,
    const float* __restrict__ we, const float* __restrict__ pe,
    const float* __restrict__ te, const float* __restrict__ lw,
    const float* __restrict__ lb, float* __restrict__ x32, u16* __restrict__ xb)
{
  int row  = blockIdx.x * 4 + (threadIdx.x >> 6);
  int lane = threadIdx.x & 63;
  int l  = row & (L_ - 1);
  int id = ids[row];
  int tt = tts[row];
  const float* wr = we + (size_t)id * DM_;
  const float* pr = pe + (size_t)l  * DM_;
  const float* tr = te + (size_t)tt * DM_;
  float v[12]; float s = 0.f;
  #pragma unroll
  for (int j = 0; j < 12; j++) { int c = j*64 + lane; v[j] = wr[c] + pr[c] + tr[c]; s += v[j]; }
  s = wredsum(s);
  float m = s * (1.f/768.f);
  float q = 0.f;
  #pragma unroll
  for (int j = 0; j < 12; j++) { float d = v[j] - m; q += d*d; }
  q = wredsum(q);
  float rs = rsqrtf(q * (1.f/768.f) + EMB_EPS_);
  float* xo = x32 + (size_t)row * DM_;
  u16*   bo = xb  + (size_t)row * DM_;
  #pragma unroll
  for (int j = 0; j < 12; j++) {
    int c = j*64 + lane;
    float o = (v[j] - m) * rs * lw[c] + lb[c];
    xo[c] = o; bo[c] = f2b(o);
  }
}

// ---------------- residual + LN (x32 f32 master; t is bf16) ----------------
__global__ __launch_bounds__(256) void ln_res(
    float* __restrict__ x32, const u16* __restrict__ t16,
    const float* __restrict__ lw, const float* __restrict__ lb,
    u16* __restrict__ xb, float eps)
{
  int row  = blockIdx.x * 4 + (threadIdx.x >> 6);
  int lane = threadIdx.x & 63;
  float* xr = x32 + (size_t)row * DM_;
  const u16* tr = t16 + (size_t)row * DM_;
  float v[12]; float s = 0.f;
  #pragma unroll
  for (int j = 0; j < 12; j++) { int c = j*64 + lane; v[j] = xr[c] + b2f(tr[c]); s += v[j]; }
  s = wredsum(s);
  float m = s * (1.f/768.f);
  float q = 0.f;
  #pragma unroll
  for (int j = 0; j < 12; j++) { float d = v[j] - m; q += d*d; }
  q = wredsum(q);
  float rs = rsqrtf(q * (1.f/768.f) + eps);
  u16* bo = xb + (size_t)row * DM_;
  #pragma unroll
  for (int j = 0; j < 12; j++) {
    int c = j*64 + lane;
    float o = (v[j] - m) * rs * lw[c] + lb[c];
    xr[c] = o; bo[c] = f2b(o);
  }
}

// ---------------- GEMM (all shapes): BM=128, BN=64, BK=64, bf16 out + bias ----------------
// Highest-occupancy member of the family (24 KB LDS, ~48-70 VGPR).
// Both-sides XOR swizzle: linear gld16 dest, pre-swizzled global source group
// (lane&7)^(row&7), read group (kk*4+g)^(lr&7).
// Epilogue: fragments -> LDS (reuse sA, exactly 16 KB) -> coalesced uint4 stores
// (32 scalar u16 stores/thread -> 4 vector stores; kills the short-K fixed cost).
// EPI: 0 = bf16 out, 2 = gelu(erf)->bf16, 4 = QKV fused (elu+1 on cols<1536)
template<int EPI>
__global__ __launch_bounds__(256)
void gemm_n64(const u16* __restrict__ A, const u16* __restrict__ Bw,
              const float* __restrict__ bias, u16* __restrict__ Ct,
              int M, int N, int K, int ldc)
{
  __shared__ alignas(16) u16 sA[128*64];
  __shared__ alignas(16) u16 sB[64*64];
  const int tid  = threadIdx.x;
  const int lane = tid & 63;
  const int w    = tid >> 6;
  const int row0 = blockIdx.x * 128;
  const int col0 = blockIdx.y * 64;
  const int lr = lane & 15;
  const int g  = lane >> 4;
  const int srow = lane >> 3;
  const int acol = (((lane & 7) ^ srow) * 8);

  f32x4 acc[2][4];
  #pragma unroll
  for (int i = 0; i < 2; i++)
    #pragma unroll
    for (int j = 0; j < 4; j++) acc[i][j] = (f32x4){0.f,0.f,0.f,0.f};

  const u16* ApA = A  + (size_t)(row0)*K;
  const u16* BpB = Bw + (size_t)(col0)*K;

  for (int kt = 0; kt < K; kt += 64) {
    #pragma unroll
    for (int j = 0; j < 4; j++)
      gld16(ApA + (size_t)(w*32 + j*8 + srow)*K + kt + acol, sA + (w*32 + j*8)*64);
    #pragma unroll
    for (int j = 0; j < 2; j++)
      gld16(BpB + (size_t)(w*16 + j*8 + srow)*K + kt + acol, sB + (w*16 + j*8)*64);
    __syncthreads();
    #pragma unroll
    for (int kk = 0; kk < 2; kk++) {
      const int gg = ((kk*4 + g) ^ (lr & 7)) * 8;
      bf16x8 af[2], bv[4];
      #pragma unroll
      for (int m = 0; m < 2; m++) af[m] = *(const bf16x8*)(sA + (w*32 + m*16 + lr)*64 + gg);
      #pragma unroll
      for (int n = 0; n < 4; n++) bv[n] = *(const bf16x8*)(sB + (n*16 + lr)*64 + gg);
      #pragma unroll
      for (int m = 0; m < 2; m++)
        #pragma unroll
        for (int n = 0; n < 4; n++)
          acc[m][n] = __builtin_amdgcn_mfma_f32_16x16x32_bf16(af[m], bv[n], acc[m][n], 0, 0, 0);
    }
    __syncthreads();
  }

  // ---- epilogue: apply bias/activation, park C tile in sA (u16), store vectorized ----
  #pragma unroll
  for (int m = 0; m < 2; m++) {
    const int lrow = w*32 + m*16 + (lane >> 4) * 4;   // local row in [0,128)
    #pragma unroll
    for (int n = 0; n < 4; n++) {
      const int col = n*16 + lr;                      // local col in [0,64)
      const float bvb = bias[col0 + col];
      #pragma unroll
      for (int r = 0; r < 4; r++) {
        float v = acc[m][n][r] + bvb;
        if constexpr (EPI == 4) { if (col0 + col < 2*DM_) v = v > 0.f ? v + 1.f : __expf(v); }
        if constexpr (EPI == 2) v = 0.5f * v * (1.f + erff(v * 0.70710678118654752f));
        sA[(lrow + r)*64 + col] = f2b(v);
      }
    }
  }
  __syncthreads();
  #pragma unroll
  for (int i = 0; i < 4; i++) {
    const int idx = i*256 + tid;
    const int row = idx >> 3;            // [0,128)
    const int c16 = (idx & 7) * 8;       // 8 u16 = 16 B
    *(uint4*)(Ct + (size_t)(row0 + row)*ldc + col0 + c16) = *(const uint4*)(sA + row*64 + c16);
  }
}

// ---------------- KV stage 1: per-(bh, 256-seq-chunk) partial outer product ----------------
__global__ __launch_bounds__(256) void kv_part(
    const u16* __restrict__ qkv, const float* __restrict__ mask,
    float* __restrict__ kvp, float* __restrict__ ksp)
{
  __shared__ float sK[64*64];
  __shared__ float sV[64*64];
  const int bh = blockIdx.x;
  const int b = bh / H_, h = bh % H_;
  const int s0 = blockIdx.y * 256;
  const int t = threadIdx.x;
  const u16* kb = qkv + DM_;
  const u16* vb = qkv + 2*DM_;
  const int m0 = (t >> 4) * 4;
  const int d0 = (t & 15) * 4;
  float acc[4][4] = {{0.f}};
  float ks[4] = {0.f, 0.f, 0.f, 0.f};

  for (int cc = 0; cc < 4; cc++) {
    __syncthreads();   // previous sub-chunk's reads done before overwrite
    #pragma unroll
    for (int r = 0; r < 2; r++) {
      int idx = r*256 + t;
      int sr = idx >> 3;
      int c  = (idx & 7) * 8;
      int sg = s0 + cc*64 + sr;
      size_t base = ((size_t)(b*L_ + sg)) * QLD_ + h*DH_ + c;
      uint4 kk = *(const uint4*)(kb + base);
      uint4 vv = *(const uint4*)(vb + base);
      float mk = mask[b*L_ + sg];
      const u16* kp = (const u16*)&kk;
      const u16* vp = (const u16*)&vv;
      #pragma unroll
      for (int j = 0; j < 8; j++) {
        sK[sr*64 + c + j] = b2f(kp[j]) * mk;
        sV[sr*64 + c + j] = b2f(vp[j]);
      }
    }
    __syncthreads();
    for (int s = 0; s < 64; s++) {
      float4 vm = *(const float4*)(sV + s*64 + m0);
      float4 kk = *(const float4*)(sK + s*64 + d0);
      float vmv[4] = {vm.x, vm.y, vm.z, vm.w};
      float kkv[4] = {kk.x, kk.y, kk.z, kk.w};
      #pragma unroll
      for (int i = 0; i < 4; i++)
        #pragma unroll
        for (int j = 0; j < 4; j++) acc[i][j] += vmv[i] * kkv[j];
      if (t < 16) { ks[0] += kkv[0]; ks[1] += kkv[1]; ks[2] += kkv[2]; ks[3] += kkv[3]; }
    }
  }
  float* o = kvp + ((size_t)bh*NCH_ + blockIdx.y) * 4096;
  #pragma unroll
  for (int i = 0; i < 4; i++) {
    float4 wv = {acc[i][0], acc[i][1], acc[i][2], acc[i][3]};
    *(float4*)(o + (m0 + i)*64 + d0) = wv;
  }
  if (t < 16) {
    float* ko = ksp + ((size_t)bh*NCH_ + blockIdx.y) * 64;
    #pragma unroll
    for (int j = 0; j < 4; j++) ko[d0 + j] = ks[j];
  }
}

// ---------------- KV stage 2: reduce over chunks ----------------
__global__ __launch_bounds__(256) void kv_reduce(
    const float* __restrict__ kvp, const float* __restrict__ ksp,
    float* __restrict__ kv, float* __restrict__ ksum)
{
  const int bh = blockIdx.x;
  const int i = blockIdx.y * 256 + threadIdx.x;
  float s = 0.f;
  #pragma unroll
  for (int c = 0; c < NCH_; c++) s += kvp[((size_t)bh*NCH_ + c)*4096 + i];
  kv[(size_t)bh*4096 + i] = s;
  if (blockIdx.y == 0 && threadIdx.x < 64) {
    float q = 0.f;
    #pragma unroll
    for (int c = 0; c < NCH_; c++) q += ksp[((size_t)bh*NCH_ + c)*64 + threadIdx.x];
    ksum[bh*64 + threadIdx.x] = q;
  }
}

// ---------------- attn: a[l,h,m] = Z * sum_d Q[l,h,d]*KV[h,m,d] (MFMA) ----------------
__global__ __launch_bounds__(256) void attn_av(
    const u16* __restrict__ qkv, const float* __restrict__ kv,
    const float* __restrict__ ksum, u16* __restrict__ ab)
{
  __shared__ alignas(16) u16 sQ[128*72];
  __shared__ alignas(16) u16 sKV[64*72];
  __shared__ float sKs[64];
  __shared__ float sZ[128];
  const int bh = blockIdx.x;
  const int b = bh / H_, h = bh % H_;
  const int l0 = blockIdx.y * 128;
  const int t = threadIdx.x;
  const int lane = t & 63;
  const int w = t >> 6;
  // stage KV (f32 -> bf16)
  for (int i = t; i < 4096; i += 256)
    sKV[(i >> 6)*72 + (i & 63)] = f2b(kv[(size_t)bh*4096 + i]);
  if (t < 64) sKs[t] = ksum[bh*64 + t];
  // stage Q (bf16, from fused qkv)
  #pragma unroll
  for (int r = 0; r < 4; r++) {
    int idx = r*256 + t;
    int s = idx >> 3;
    int c = (idx & 7) * 8;
    *(uint4*)(sQ + s*72 + c) =
        *(const uint4*)(qkv + ((size_t)(b*L_ + l0 + s)) * QLD_ + h*DH_ + c);
  }
  __syncthreads();
  // Z per row: 2 threads/row
  {
    int row = t >> 1, half = t & 1;
    float zd = 0.f;
    #pragma unroll
    for (int ch = 0; ch < 4; ch++) {
      bf16x8 qv = *(const bf16x8*)(sQ + row*72 + half*32 + ch*8);
      #pragma unroll
      for (int j = 0; j < 8; j++) zd += (float)qv[j] * sKs[half*32 + ch*8 + j];
    }
    zd += __shfl_xor(zd, 1, 64);
    if (half == 0) sZ[row] = 1.f / (zd + ATT_EPS_);
  }
  // MFMA: wave w -> rows w*32..w*32+31, cols 0..63
  const int lr = lane & 15, lk = (lane >> 4) * 8;
  f32x4 acc[2][4];
  #pragma unroll
  for (int m = 0; m < 2; m++)
    #pragma unroll
    for (int n = 0; n < 4; n++) acc[m][n] = (f32x4){0.f,0.f,0.f,0.f};
  #pragma unroll
  for (int kk = 0; kk < 2; kk++) {
    bf16x8 af[2], bv[4];
    #pragma unroll
    for (int m = 0; m < 2; m++) af[m] = *(const bf16x8*)(sQ + (w*32 + m*16 + lr)*72 + kk*32 + lk);
    #pragma unroll
    for (int n = 0; n < 4; n++) bv[n] = *(const bf16x8*)(sKV + (n*16 + lr)*72 + kk*32 + lk);
    #pragma unroll
    for (int m = 0; m < 2; m++)
      #pragma unroll
      for (int n = 0; n < 4; n++)
        acc[m][n] = __builtin_amdgcn_mfma_f32_16x16x32_bf16(af[m], bv[n], acc[m][n], 0, 0, 0);
  }
  __syncthreads();   // sZ visible
  #pragma unroll
  for (int m = 0; m < 2; m++) {
    const int row_l = w*32 + m*16 + (lane >> 4) * 4;
    #pragma unroll
    for (int n = 0; n < 4; n++) {
      const int col = n*16 + lr;
      #pragma unroll
      for (int r = 0; r < 4; r++) {
        float v = acc[m][n][r] * sZ[row_l + r];
        ab[((size_t)(b*L_ + l0 + row_l + r)) * DM_ + h*DH_ + col] = f2b(v);
      }
    }
  }
}

// ---------------- final copy ----------------
__global__ __launch_bounds__(256) void copyf4(const float4* __restrict__ in,
                                              float4* __restrict__ out, int n4) {
  int i = blockIdx.x * 256 + threadIdx.x;
  if (i < n4) out[i] = in[i];
}

extern "C" void kernel_launch(void* const* d_in, const int* in_sizes, int n_in,
                              void* d_out, int out_size, void* d_ws, size_t ws_size,
                              hipStream_t stream)
{
  const int*   ids  = (const int*)d_in[0];
  const float* mask = (const float*)d_in[1];
  const int*   tts  = (const int*)d_in[2];
  const float* we   = (const float*)d_in[3];
  const float* pe   = (const float*)d_in[4];
  const float* te   = (const float*)d_in[5];
  const float* elw  = (const float*)d_in[6];
  const float* elb  = (const float*)d_in[7];
  const float* Wq   = (const float*)d_in[8];
  const float* bq   = (const float*)d_in[9];
  const float* Wk   = (const float*)d_in[10];
  const float* bk   = (const float*)d_in[11];
  const float* Wv   = (const float*)d_in[12];
  const float* bv   = (const float*)d_in[13];
  const float* Wo   = (const float*)d_in[14];
  const float* bo   = (const float*)d_in[15];
  const float* l1w  = (const float*)d_in[16];
  const float* l1b  = (const float*)d_in[17];
  const float* W1   = (const float*)d_in[18];
  const float* b1   = (const float*)d_in[19];
  const float* W2   = (const float*)d_in[20];
  const float* b2   = (const float*)d_in[21];
  const float* l2w  = (const float*)d_in[22];
  const float* l2b  = (const float*)d_in[23];

  char* p = (char*)d_ws;
  auto alloc = [&](size_t n) -> char* {
    char* r = p; p += (n + 255) & ~(size_t)255; return r;
  };
  const size_t SQ = (size_t)NL_ * DM_ * DM_;
  const size_t SF = (size_t)NL_ * DFF_ * DM_;
  u16*  wqkvb = (u16*)alloc((size_t)NL_ * QLD_ * DM_ * 2);
  u16*  wob   = (u16*)alloc(SQ * 2);
  u16*  w1b   = (u16*)alloc(SF * 2);
  u16*  w2b   = (u16*)alloc(SF * 2);
  float* bqkv = (float*)alloc((size_t)NL_ * QLD_ * 4);
  float* x32  = (float*)alloc((size_t)M_ * DM_ * 4);
  u16*  t16   = (u16*)alloc((size_t)M_ * DM_ * 2);
  u16*  xb    = (u16*)alloc((size_t)M_ * DM_ * 2);
  u16*  qkv   = (u16*)alloc((size_t)M_ * QLD_ * 2);
  u16*  abuf  = (u16*)alloc((size_t)M_ * DM_ * 2);
  u16*  ybuf  = (u16*)alloc((size_t)M_ * DFF_ * 2);
  float* kvb  = (float*)alloc((size_t)(B_*H_*DH_*DH_ + B_*H_*DH_) * 4);
  float* ksm  = kvb + (size_t)B_*H_*DH_*DH_;
  float* ksp  = (float*)alloc((size_t)B_*H_*NCH_*DH_ * 4);
  float* kvp  = (float*)alloc((size_t)B_*H_*NCH_*DH_*DH_ * 4);   // 6.3 MB partials

  const int nq4 = (int)(SQ/4);
  cvt_bf16_qkv<<<(nq4+255)/256, 256, 0, stream>>>(Wq, wqkvb, 0);
  cvt_bf16_qkv<<<(nq4+255)/256, 256, 0, stream>>>(Wk, wqkvb, DM_);
  cvt_bf16_qkv<<<(nq4+255)/256, 256, 0, stream>>>(Wv, wqkvb, 2*DM_);
  cvt_bf16<<<nq4/256, 256, 0, stream>>>(Wo, wob, nq4);
  cvt_bf16<<<(int)(SF/4/256), 256, 0, stream>>>(W1, w1b, (int)(SF/4));
  cvt_bf16<<<(int)(SF/4/256), 256, 0, stream>>>(W2, w2b, (int)(SF/4));
  fuse_bias<<<(NL_*QLD_+255)/256, 256, 0, stream>>>(bq, bk, bv, bqkv);

  embed_ln<<<M_/4, 256, 0, stream>>>(ids, tts, we, pe, te, elw, elb, x32, xb);

  for (int il = 0; il < NL_; ++il) {
    const u16* wqkv = wqkvb + (size_t)il * QLD_ * DM_;
    const u16* wo = wob + (size_t)il * DM_ * DM_;
    const u16* w1 = w1b + (size_t)il * DFF_ * DM_;
    const u16* w2 = w2b + (size_t)il * DFF_ * DM_;

    gemm_n64<4><<<dim3(M_/128, QLD_/64), 256, 0, stream>>>(
        xb, wqkv, bqkv + (size_t)il*QLD_, qkv, M_, QLD_, DM_, QLD_);

    kv_part<<<dim3(B_*H_, NCH_), 256, 0, stream>>>(qkv, mask, kvp, ksp);
    kv_reduce<<<dim3(B_*H_, 16), 256, 0, stream>>>(kvp, ksp, kvb, ksm);
    attn_av<<<dim3(B_*H_, L_/128), 256, 0, stream>>>(qkv, kvb, ksm, abuf);

    gemm_n64<0><<<dim3(M_/128, DM_/64), 256, 0, stream>>>(
        abuf, wo, bo + (size_t)il*DM_, t16, M_, DM_, DM_, DM_);
    ln_res<<<M_/4, 256, 0, stream>>>(x32, t16, l1w + (size_t)il*DM_, l1b + (size_t)il*DM_, xb, LN_EPS_);

    gemm_n64<2><<<dim3(M_/128, DFF_/64), 256, 0, stream>>>(
        xb, w1, b1 + (size_t)il*DFF_, ybuf, M_, DFF_, DM_, DFF_);
    gemm_n64<0><<<dim3(M_/128, DM_/64), 256, 0, stream>>>(
        ybuf, w2, b2 + (size_t)il*DM_, t16, M_, DM_, DFF_, DM_);
    ln_res<<<M_/4, 256, 0, stream>>>(x32, t16, l2w + (size_t)il*DM_, l2b + (size_t)il*DM_, xb, LN_EPS_);
  }

  copyf4<<<(M_*DM_/4)/256, 256, 0, stream>>>((const float4*)x32, (float4*)d_out, M_*DM_/4);
}